// Round 11
// baseline (464.499 us; speedup 1.0000x reference)
//
#include <hip/hip_runtime.h>
#include <stdint.h>

#define NB 64
#define NO 32
#define NI 512
#define ND 64

typedef __attribute__((ext_vector_type(8))) short short8;
typedef __attribute__((ext_vector_type(4))) float f32x4;

// async global->LDS DMA, 16 B/lane. Global addr per-lane; LDS base wave-uniform,
// lane i lands at base + 16*i (m104/m108 semantics).
#define GL2LDS(g, s) __builtin_amdgcn_global_load_lds( \
    (const __attribute__((address_space(1))) void*)(g), \
    (__attribute__((address_space(3))) void*)(s), 16, 0, 0)

__device__ __forceinline__ float blo(unsigned int u) {
    union { unsigned int i; float f; } v; v.i = u << 16; return v.f;
}
__device__ __forceinline__ float bhi(unsigned int u) {
    union { unsigned int i; float f; } v; v.i = u & 0xFFFF0000u; return v.f;
}
__device__ __forceinline__ unsigned short f2bf(float f) {
    union { float f; unsigned int i; } v; v.f = f;
    return (unsigned short)((v.i + 0x7FFFu + ((v.i >> 16) & 1u)) >> 16);
}
__device__ __forceinline__ short8 pack8(const float4 a, const float4 b) {
    short8 r;
    r[0] = (short)f2bf(a.x); r[1] = (short)f2bf(a.y);
    r[2] = (short)f2bf(a.z); r[3] = (short)f2bf(a.w);
    r[4] = (short)f2bf(b.x); r[5] = (short)f2bf(b.y);
    r[6] = (short)f2bf(b.z); r[7] = (short)f2bf(b.w);
    return r;
}
__device__ __forceinline__ void ld_a(float4 r[4], const float* __restrict__ p) {
    r[0] = *(const float4*)(p);
    r[1] = *(const float4*)(p + 4);
    r[2] = *(const float4*)(p + 32);
    r[3] = *(const float4*)(p + 36);
}

// K1: x_hat = W x, stored bf16 in PERMUTED d-order: d' = 4c + td (d = 16 td + c).
// Layout xh[o][b][i][d']. Counted-vmcnt pipeline (r10, verified: gemm 200 ->
// <157 us). ROUND-11: triple buffer -> DOUBLE buffer (48 -> 32 KB LDS). The 3rd
// buffer only existed because the old vmcnt(0)-drain barrier defeated prefetch;
// with counted vmcnt the 2-buffer prefetch window (stage ii+2 issued at iter-ii
// end, needed at iter ii+2 top = ~1.5 iters ~ 10 us >> HBM latency) is
// sufficient. 32 KB -> 5 blocks/CU (was 3): 12 -> 20 waves/CU.
// Safety (order-robust, any within-iter vmem permutation): at bar1 of iter ii,
// stage(ii) was issued at the END of iter ii-2, and iter ii-1 issued >=8 vmem
// ops after it (4 ld + 4 stage for ii-1<6, +4 stores for ii>=3; ii-1=6 issues
// exactly 8) -> stage(ii) is >=9th-newest -> s_waitcnt vmcnt(8) always drains
// it. bar2 (post-compute) orders buffer reuse: stage(ii+2) into buf ii%2 only
// after ALL waves finished reading buf ii%2. Prologue vmcnt(0) covers ii=0/1.
__global__ __launch_bounds__(256) void k_gemm(const float* __restrict__ x,
                                              const float* __restrict__ w,
                                              unsigned short* __restrict__ xh) {
    __shared__ float Wl[2][4096];            // 32 KB, double-buffered W tiles
    const int o  = blockIdx.x & 31;
    const int ig = blockIdx.x >> 5;
    const int t  = threadIdx.x;
    const int wv = t >> 6;
    const int l  = t & 63;
    const int q  = l >> 4;
    const int c  = l & 15;

    const float* wbase = w + ((size_t)o * NI + ig * 8) * 4096;

    auto stage = [&](int buf, int ii) {
        const float* src = wbase + (size_t)ii * 4096;
        #pragma unroll
        for (int k = 0; k < 4; ++k) {
            const int s = wv * 256 + k * 64 + l;
            const int r = s >> 4;
            const int g = (s & 15) ^ (r & 15);
            GL2LDS(src + r * 64 + g * 4, &Wl[buf][(wv * 256 + k * 64) * 4]);
        }
    };

    const float* ap0 = x + ((size_t)(16 * wv + c) * NI + ig * 8) * 64 + q * 8;
    float4 ra[4], na[4];
    ld_a(ra, ap0);
    stage(0, 0);
    stage(1, 1);
    // prologue drain: tiles 0 and 1 guaranteed in LDS before the loop.
    asm volatile("s_waitcnt vmcnt(0)" ::: "memory");

    uint2 cst[4];
    #pragma unroll 1
    for (int ii = 0; ii < 8; ++ii) {
        // counted drain: completes stage(ii) (>=9th-newest for all ii, see
        // header proof); keeps next stage + x prefetch in flight.
        asm volatile("s_waitcnt vmcnt(8)" ::: "memory");
        __builtin_amdgcn_s_barrier();        // bar1: buf ii%2 staged for all waves
        if (ii > 0) {                        // store iter ii-1's C
            #pragma unroll
            for (int rr = 0; rr < 4; ++rr) {
                const int bq = 16 * wv + 4 * q + rr;
                *(uint2*)(xh + (((size_t)o * NB + bq) * NI + (ig * 8 + ii - 1)) * ND + 4 * c) = cst[rr];
            }
        }
        if (ii < 7) ld_a(na, ap0 + (ii + 1) * 64);

        const float* Wb = Wl[ii & 1];
        const short8 a0 = pack8(ra[0], ra[1]);
        const short8 a1 = pack8(ra[2], ra[3]);
        f32x4 acc[4];
        #pragma unroll
        for (int td = 0; td < 4; ++td) {
            const int r = 16 * td + c;
            const float4 f0 = *(const float4*)&Wb[(r * 16 + ((2 * q)     ^ c)) * 4];
            const float4 f1 = *(const float4*)&Wb[(r * 16 + ((2 * q + 1) ^ c)) * 4];
            const float4 f2 = *(const float4*)&Wb[(r * 16 + ((2 * q + 8) ^ c)) * 4];
            const float4 f3 = *(const float4*)&Wb[(r * 16 + ((2 * q + 9) ^ c)) * 4];
            const short8 b0 = pack8(f0, f1);
            const short8 b1 = pack8(f2, f3);
            f32x4 z = {0.f, 0.f, 0.f, 0.f};
            z = __builtin_amdgcn_mfma_f32_16x16x32_bf16(a0, b0, z, 0, 0, 0);
            z = __builtin_amdgcn_mfma_f32_16x16x32_bf16(a1, b1, z, 0, 0, 0);
            acc[td] = z;
        }
        #pragma unroll
        for (int rr = 0; rr < 4; ++rr) {
            cst[rr].x = (unsigned int)f2bf(acc[0][rr]) | ((unsigned int)f2bf(acc[1][rr]) << 16);
            cst[rr].y = (unsigned int)f2bf(acc[2][rr]) | ((unsigned int)f2bf(acc[3][rr]) << 16);
        }
        #pragma unroll
        for (int j = 0; j < 4; ++j) ra[j] = na[j];

        __builtin_amdgcn_s_barrier();        // bar2: all waves done reading buf ii%2
        if (ii < 6) stage(ii & 1, ii + 2);   // restage just-freed buffer
    }
    #pragma unroll
    for (int rr = 0; rr < 4; ++rr) {         // last iteration's C
        const int bq = 16 * wv + 4 * q + rr;
        *(uint2*)(xh + (((size_t)o * NB + bq) * NI + (ig * 8 + 7)) * ND + 4 * c) = cst[rr];
    }
}

// Softmax stats per (b,i): m = max_o logits, 1/Z. 128 blocks. (round-0 verified)
__global__ __launch_bounds__(256) void k_soft(const float* __restrict__ b_in,
                                              float* __restrict__ mz) {
    const int p = blockIdx.x * 256 + threadIdx.x;        // p = b*512 + i
    const int b = p >> 9, i = p & 511;
    const float* bp = b_in + (size_t)b * NO * NI + i;
    float v[NO];
    #pragma unroll
    for (int oo = 0; oo < NO; ++oo) v[oo] = bp[(size_t)oo * NI];
    float m = v[0];
    #pragma unroll
    for (int oo = 1; oo < NO; ++oo) m = fmaxf(m, v[oo]);
    float Z = 0.f;
    #pragma unroll
    for (int oo = 0; oo < NO; ++oo) Z += __expf(v[oo] - m);
    mz[p] = m;
    mz[NB * NI + p] = 1.0f / Z;
}

// Routing step, block = (b,o). Hybrid tile: rows 0..255 DMA'd to LDS (32 KB),
// rows 256..511 in registers (8 uint4/thread). Static LDS 35.3 KB -> 4
// blocks/CU. All d-indexed data in d'-space; STEP==2 output write remaps
// d = 16*(t&3) + (t>>2). (round-0 verified source, unchanged — control)
template<int STEP>
__global__ __launch_bounds__(256) void k_route(const unsigned short* __restrict__ xh,
                                               const float* __restrict__ b_in,
                                               const float* __restrict__ mz,
                                               float* __restrict__ b_out,
                                               float* __restrict__ outp) {
    __shared__ unsigned short tile[256 * ND];  // 32 KB, rows 0..255
    __shared__ float c_s[NI];
    __shared__ float P[4 * 64];
    __shared__ float o_s[64];

    const int t  = threadIdx.x;
    const int b  = blockIdx.x >> 5;
    const int o  = blockIdx.x & 31;
    const int wv = t >> 6;
    const int l  = t & 63;
    const int dg = t & 7;
    const int ip = t >> 3;

    const unsigned short* gsrc = xh + ((size_t)o * NB + b) * NI * ND;

    // Register half first (latency overlapped by DMA issue + softmax).
    uint4 raw[8];
    #pragma unroll
    for (int k = 0; k < 8; ++k)
        raw[k] = *(const uint4*)(gsrc + (size_t)(256 + 32 * k + ip) * ND + dg * 8);

    // DMA half: wave wv covers 8 KB as 8 x 1-KB instrs (linear layout).
    #pragma unroll
    for (int k = 0; k < 8; ++k)
        GL2LDS(gsrc + wv * 4096 + k * 512 + l * 8, tile + wv * 4096 + k * 512);

    const float* bp = (STEP > 0) ? (b_in + ((size_t)b * NO + o) * NI) : nullptr;
    if (STEP > 0) {
        const float* mrow = mz + (size_t)b * NI;
        const float* zrow = mz + (size_t)(NB * NI) + (size_t)b * NI;
        #pragma unroll
        for (int s = 0; s < 2; ++s) {
            const int i = t + s * 256;
            c_s[i] = __expf(bp[i] - mrow[i]) * zrow[i];
        }
    }
    __syncthreads();                                     // DMA + c_s visible

    // c-weighted accumulation of s[d'] over both halves.
    float acc[8] = {0, 0, 0, 0, 0, 0, 0, 0};
    #pragma unroll
    for (int k = 0; k < 8; ++k) {                        // LDS half, rows 32k+ip
        const int i = 32 * k + ip;
        const uint4 rl = *(const uint4*)(tile + i * ND + dg * 8);
        const float cw = (STEP == 0) ? 0.03125f : c_s[i];
        acc[0] += cw * blo(rl.x); acc[1] += cw * bhi(rl.x);
        acc[2] += cw * blo(rl.y); acc[3] += cw * bhi(rl.y);
        acc[4] += cw * blo(rl.z); acc[5] += cw * bhi(rl.z);
        acc[6] += cw * blo(rl.w); acc[7] += cw * bhi(rl.w);
    }
    #pragma unroll
    for (int k = 0; k < 8; ++k) {                        // register half, rows 256+32k+ip
        const float cw = (STEP == 0) ? 0.03125f : c_s[256 + 32 * k + ip];
        acc[0] += cw * blo(raw[k].x); acc[1] += cw * bhi(raw[k].x);
        acc[2] += cw * blo(raw[k].y); acc[3] += cw * bhi(raw[k].y);
        acc[4] += cw * blo(raw[k].z); acc[5] += cw * bhi(raw[k].z);
        acc[6] += cw * blo(raw[k].w); acc[7] += cw * bhi(raw[k].w);
    }
    #pragma unroll
    for (int j = 0; j < 8; ++j) {          // reduce over ip within wave (bits 3..5)
        acc[j] += __shfl_xor(acc[j], 8);
        acc[j] += __shfl_xor(acc[j], 16);
        acc[j] += __shfl_xor(acc[j], 32);
    }
    if (l < 8) {
        #pragma unroll
        for (int j = 0; j < 8; ++j) P[wv * 64 + l * 8 + j] = acc[j];
    }
    __syncthreads();

    // Wave 0: finish s[d'], squash, emit out vector (o_s in d'-space).
    if (t < 64) {
        const float sv = P[t] + P[64 + t] + P[128 + t] + P[192 + t];
        float s2 = sv * sv;
        #pragma unroll
        for (int m = 1; m < 64; m <<= 1) s2 += __shfl_xor(s2, m);
        const float n = sqrtf(s2);
        const float sc = (s2 / (1.0f + s2)) / (n + 1e-8f);
        const float ov = sv * sc;
        o_s[t] = ov;
        if (STEP == 2) {
            const int d = 16 * (t & 3) + (t >> 2);       // d' -> d remap
            outp[((size_t)b * NO + o) * ND + d] = ov;
        }
    }
    __syncthreads();

    // b-update: dot per row (d'-space), reduce across dg (bits 0..2).
    if (STEP < 2) {
        float oc[8];
        #pragma unroll
        for (int j = 0; j < 8; ++j) oc[j] = o_s[dg * 8 + j];
        float w1 = 0.f, w2 = 0.f;
        #pragma unroll
        for (int k = 0; k < 8; ++k) {                    // LDS half
            const uint4 rl = *(const uint4*)(tile + (32 * k + ip) * ND + dg * 8);
            float pd = blo(rl.x) * oc[0] + bhi(rl.x) * oc[1]
                     + blo(rl.y) * oc[2] + bhi(rl.y) * oc[3]
                     + blo(rl.z) * oc[4] + bhi(rl.z) * oc[5]
                     + blo(rl.w) * oc[6] + bhi(rl.w) * oc[7];
            pd += __shfl_xor(pd, 1);
            pd += __shfl_xor(pd, 2);
            pd += __shfl_xor(pd, 4);
            if (k == dg) w1 = pd;
        }
        #pragma unroll
        for (int k = 0; k < 8; ++k) {                    // register half
            float pd = blo(raw[k].x) * oc[0] + bhi(raw[k].x) * oc[1]
                     + blo(raw[k].y) * oc[2] + bhi(raw[k].y) * oc[3]
                     + blo(raw[k].z) * oc[4] + bhi(raw[k].z) * oc[5]
                     + blo(raw[k].w) * oc[6] + bhi(raw[k].w) * oc[7];
            pd += __shfl_xor(pd, 1);
            pd += __shfl_xor(pd, 2);
            pd += __shfl_xor(pd, 4);
            if (k == dg) w2 = pd;
        }
        const int i1 = 32 * dg + ip;                     // row from LDS half
        const int i2 = 256 + 32 * dg + ip;               // row from register half
        float* bo = b_out + ((size_t)b * NO + o) * NI;
        bo[i1] = ((STEP == 0) ? 0.f : bp[i1]) + w1;
        bo[i2] = ((STEP == 0) ? 0.f : bp[i2]) + w2;
    }
}

extern "C" void kernel_launch(void* const* d_in, const int* in_sizes, int n_in,
                              void* d_out, int out_size, void* d_ws, size_t ws_size,
                              hipStream_t stream) {
    const float* x = (const float*)d_in[0];        // [64,512,64] fp32
    const float* w = (const float*)d_in[1];        // [32,512,64,64] fp32
    float* outp = (float*)d_out;                   // [64,32,64] fp32

    char* ws = (char*)d_ws;
    unsigned short* xh = (unsigned short*)ws;                       // 128 MiB bf16 xh[o][b][i][d']
    float* ba = (float*)(ws + (size_t)134217728);                   // 4 MiB logits A
    float* bb = (float*)(ws + (size_t)134217728 + 4194304);         // 4 MiB logits B
    float* mz = (float*)(ws + (size_t)134217728 + 2 * 4194304);     // 256 KiB m / 1/Z

    k_gemm<<<dim3(2048), dim3(256), 0, stream>>>(x, w, xh);
    k_route<0><<<dim3(2048), dim3(256), 0, stream>>>(xh, nullptr, nullptr, ba, nullptr);
    k_soft<<<dim3(128), dim3(256), 0, stream>>>(ba, mz);
    k_route<1><<<dim3(2048), dim3(256), 0, stream>>>(xh, ba, mz, bb, nullptr);
    k_soft<<<dim3(128), dim3(256), 0, stream>>>(bb, mz);
    k_route<2><<<dim3(2048), dim3(256), 0, stream>>>(xh, bb, mz, nullptr, outp);
}